// Round 1
// 916.960 us; speedup vs baseline: 1.1125x; 1.1125x over previous
//
#include <hip/hip_runtime.h>
#include <stdint.h>

#define D_DIM 512
#define H_DIM 2048
#define E_NUM 8
#define TOPK_N 2

typedef __attribute__((ext_vector_type(8))) short bf16x8;
typedef __attribute__((ext_vector_type(4))) float f32x4;

// async global->LDS, 16B per lane. LDS dst must be wave-uniform; HW adds lane*16.
#define GLOAD_LDS16(gsrc, ldst)                                                     \
    __builtin_amdgcn_global_load_lds(                                               \
        (const __attribute__((address_space(1))) void*)(gsrc),                      \
        (__attribute__((address_space(3))) void*)(ldst), 16, 0, 0)

static __device__ __forceinline__ unsigned short f2bf(float f) {
    unsigned u = __float_as_uint(f);
    unsigned r = (u + 0x7fffu + ((u >> 16) & 1u)) >> 16;
    return (unsigned short)r;
}

// ---------------- init: list=-1, zrow=0 ----------------
__global__ void init_kernel(int* list_token, float* list_w, unsigned short* zrow, int cap) {
    int id = blockIdx.x * blockDim.x + threadIdx.x;
    if (id < cap) { list_token[id] = -1; list_w[id] = 0.f; }
    if (id < D_DIM) zrow[id] = 0;
}

// ---------------- gw [D][E] -> gwT [E][D] (tiny) ----------------
__global__ void gwt_kernel(const float* __restrict__ gw, float* __restrict__ gwT) {
    int id = blockIdx.x * blockDim.x + threadIdx.x;   // 4096
    int e = id >> 9, d = id & 511;
    gwT[id] = gw[d * E_NUM + e];
}

// -------- fused: x fp32 -> bf16 AND gate logits/top-2 (one pass over x) --------
__global__ void gate_cvt_kernel(const float* __restrict__ x, const float* __restrict__ gwT,
                                unsigned short* __restrict__ xb,
                                int* __restrict__ ridx, float* __restrict__ rw, int T) {
    int wave = threadIdx.x >> 6;
    int lane = threadIdx.x & 63;
    int t = blockIdx.x * 4 + wave;
    if (t >= T) return;
    const float* xr = x + (size_t)t * D_DIM + lane * 8;
    float4 a = *(const float4*)xr;
    float4 b = *(const float4*)(xr + 4);
    union { unsigned short s[8]; uint4 v; } o;
    o.s[0] = f2bf(a.x); o.s[1] = f2bf(a.y); o.s[2] = f2bf(a.z); o.s[3] = f2bf(a.w);
    o.s[4] = f2bf(b.x); o.s[5] = f2bf(b.y); o.s[6] = f2bf(b.z); o.s[7] = f2bf(b.w);
    *(uint4*)(xb + (size_t)t * D_DIM + lane * 8) = o.v;
    float acc[8];
#pragma unroll
    for (int e = 0; e < 8; ++e) {
        const float* g = gwT + e * D_DIM + lane * 8;
        float4 g0 = *(const float4*)g;
        float4 g1 = *(const float4*)(g + 4);
        acc[e] = a.x * g0.x + a.y * g0.y + a.z * g0.z + a.w * g0.w
               + b.x * g1.x + b.y * g1.y + b.z * g1.z + b.w * g1.w;
    }
#pragma unroll
    for (int off = 32; off > 0; off >>= 1) {
#pragma unroll
        for (int e = 0; e < 8; ++e) acc[e] += __shfl_xor(acc[e], off, 64);
    }
    if (lane == 0) {
        int e0 = 0; float l0 = acc[0];
#pragma unroll
        for (int e = 1; e < 8; ++e) if (acc[e] > l0) { l0 = acc[e]; e0 = e; }
        int e1 = -1; float l1 = -1e30f;
#pragma unroll
        for (int e = 0; e < 8; ++e) if (e != e0 && acc[e] > l1) { l1 = acc[e]; e1 = e; }
        float w0 = 1.f / (1.f + expf(l1 - l0));
        ridx[t * 2] = e0; ridx[t * 2 + 1] = e1;
        rw[t * 2] = w0;  rw[t * 2 + 1] = 1.f - w0;
    }
}

// ------------- transpose+convert: in fp32 [E][R][C] -> out bf16 [E][C][R] -------------
__global__ void tconv_kernel(const float* __restrict__ in, unsigned short* __restrict__ out,
                             int R, int C) {
    __shared__ float tile[32][33];
    int e = blockIdx.z;
    const float* src = in + (size_t)e * R * C;
    unsigned short* dst = out + (size_t)e * R * C;
    int c = blockIdx.x * 32 + threadIdx.x;
#pragma unroll
    for (int i = 0; i < 4; ++i) {
        int r = blockIdx.y * 32 + threadIdx.y + i * 8;
        tile[threadIdx.y + i * 8][threadIdx.x] = src[(size_t)r * C + c];
    }
    __syncthreads();
    int r2 = blockIdx.y * 32 + threadIdx.x;
#pragma unroll
    for (int i = 0; i < 4; ++i) {
        int c2 = blockIdx.x * 32 + threadIdx.y + i * 8;
        dst[(size_t)c2 * R + r2] = f2bf(tile[threadIdx.x][threadIdx.y + i * 8]);
    }
}

// ---------------- per-block histogram (LDS atomics only) ----------------
__global__ void hist_kernel(const int* __restrict__ ridx, int* __restrict__ partial, int npairs) {
    __shared__ int cnt[E_NUM];
    if (threadIdx.x < E_NUM) cnt[threadIdx.x] = 0;
    __syncthreads();
    for (int i = blockIdx.x * blockDim.x + threadIdx.x; i < npairs; i += gridDim.x * blockDim.x)
        atomicAdd(&cnt[ridx[i]], 1);
    __syncthreads();
    if (threadIdx.x < E_NUM) partial[blockIdx.x * E_NUM + threadIdx.x] = cnt[threadIdx.x];
}

// ---------------- scan: padded seg offsets + per-block bases ----------------
__global__ void scan_kernel(const int* __restrict__ partial, int* __restrict__ seg,
                            int* __restrict__ block_base) {
    __shared__ int sp[64 * E_NUM];
    __shared__ int segl[E_NUM + 1];
    int tid = threadIdx.x;
    if (tid < 64 * E_NUM) sp[tid] = partial[tid];
    __syncthreads();
    if (tid == 0) {
        int off = 0;
        for (int e = 0; e < E_NUM; ++e) {
            segl[e] = off;
            int c = 0;
            for (int b = 0; b < 64; ++b) c += sp[b * E_NUM + e];
            off += (c + 127) & ~127;
        }
        segl[E_NUM] = off;
    }
    __syncthreads();
    if (tid < E_NUM) {
        int run = segl[tid];
        for (int b = 0; b < 64; ++b) { block_base[b * E_NUM + tid] = run; run += sp[b * E_NUM + tid]; }
        seg[tid] = segl[tid];
        if (tid == 0) seg[E_NUM] = segl[E_NUM];
    }
}

// ---------------- scatter: LDS counters + precomputed block base ----------------
__global__ void scatter_kernel(const int* __restrict__ ridx, const float* __restrict__ rw,
                               const int* __restrict__ block_base,
                               int* __restrict__ list_token, float* __restrict__ list_w, int npairs) {
    __shared__ int base[E_NUM];
    __shared__ int cnt[E_NUM];
    if (threadIdx.x < E_NUM) { base[threadIdx.x] = block_base[blockIdx.x * E_NUM + threadIdx.x]; cnt[threadIdx.x] = 0; }
    __syncthreads();
    for (int i = blockIdx.x * blockDim.x + threadIdx.x; i < npairs; i += gridDim.x * blockDim.x) {
        int e = ridx[i];
        int pos = base[e] + atomicAdd(&cnt[e], 1);
        list_token[pos] = i >> 1;
        list_w[pos] = rw[i];
    }
}

// ---------------- GEMM1: h = silu(X W1) * (X W3), 128x(64+64) tile ----------------
// Double-buffered LDS: stage(t+1) issued BEFORE compute(t); single barrier per K-step
// drains vmcnt AFTER compute so global latency hides under the 32 MFMAs. (T3 min-2-phase)
__global__ __launch_bounds__(256) void gemm1_kernel(
    const unsigned short* __restrict__ xb,
    const unsigned short* __restrict__ w1t,   // [E][H][D]
    const unsigned short* __restrict__ w3t,
    const unsigned short* __restrict__ zrow,
    const int* __restrict__ list_token,
    const int* __restrict__ seg,
    unsigned short* __restrict__ hbuf,        // [chunk_slots][H]
    int chunk_base, int MT, int MG) {
    __shared__ short As[2][128 * 64];
    __shared__ short Bs[2][128 * 64];

    int bfl = blockIdx.x;
    int xcd = bfl & 7;
    int idx = bfl >> 3;
    int mlocal = idx % MG;
    int yt = idx / MG;
    int mt = mlocal * 8 + xcd;
    if (mt >= MT) return;

    int tid = threadIdx.x;
    int w = tid >> 6, l = tid & 63;
    int m0 = mt * 128;
    int slot0 = chunk_base + m0;
    int n0 = yt * 64;

    int e = 0;
#pragma unroll
    for (int i = 0; i < E_NUM - 1; ++i) if (slot0 >= seg[i + 1]) e = i + 1;
    const unsigned short* b1 = w1t + ((size_t)e * H_DIM + n0) * D_DIM;
    const unsigned short* b3 = w3t + ((size_t)e * H_DIM + n0) * D_DIM;

    int lr8 = l >> 3, p = l & 7;
    const unsigned short* aptr[4];
    const unsigned short* bptr[4];
#pragma unroll
    for (int q = 0; q < 4; ++q) {
        int row = (q * 4 + w) * 8 + lr8;       // 0..127
        int c = p ^ (row & 7);
        int tok = list_token[slot0 + row];
        aptr[q] = (tok >= 0 ? xb + (size_t)tok * D_DIM : zrow) + c * 8;
        bptr[q] = (row < 64 ? b1 + (size_t)row * D_DIM
                            : b3 + (size_t)(row - 64) * D_DIM) + c * 8;
    }

    int wm = (w & 1) * 64;
    int wn = (w >> 1) * 32;
    int lrr = l & 15;
    int lk = (l >> 4) * 8;

    f32x4 acc1[4][2] = {};
    f32x4 acc3[4][2] = {};

#define G1_STAGE(K0, BUF)                                                           \
    {                                                                               \
        _Pragma("unroll")                                                           \
        for (int q = 0; q < 4; ++q) {                                               \
            GLOAD_LDS16(aptr[q] + (K0), &As[BUF][(q * 4 + w) * 512]);               \
            GLOAD_LDS16(bptr[q] + (K0), &Bs[BUF][(q * 4 + w) * 512]);               \
        }                                                                           \
    }

#define G1_COMPUTE(BUF)                                                             \
    {                                                                               \
        _Pragma("unroll")                                                           \
        for (int ks = 0; ks < 64; ks += 32) {                                       \
            int cblk = (ks + lk) >> 3;                                              \
            bf16x8 af[4], b1f[2], b3f[2];                                           \
            _Pragma("unroll")                                                       \
            for (int i = 0; i < 4; ++i) {                                           \
                int row = wm + i * 16 + lrr;                                        \
                af[i] = *(const bf16x8*)&As[BUF][row * 64 + ((cblk ^ (row & 7)) << 3)]; \
            }                                                                       \
            _Pragma("unroll")                                                       \
            for (int j = 0; j < 2; ++j) {                                           \
                int r1 = wn + j * 16 + lrr;                                         \
                b1f[j] = *(const bf16x8*)&Bs[BUF][r1 * 64 + ((cblk ^ (r1 & 7)) << 3)]; \
                int r3 = 64 + wn + j * 16 + lrr;                                    \
                b3f[j] = *(const bf16x8*)&Bs[BUF][r3 * 64 + ((cblk ^ (r3 & 7)) << 3)]; \
            }                                                                       \
            __builtin_amdgcn_s_setprio(1);                                          \
            _Pragma("unroll")                                                       \
            for (int i = 0; i < 4; ++i)                                             \
                _Pragma("unroll")                                                   \
                for (int j = 0; j < 2; ++j) {                                       \
                    acc1[i][j] = __builtin_amdgcn_mfma_f32_16x16x32_bf16(af[i], b1f[j], acc1[i][j], 0, 0, 0); \
                    acc3[i][j] = __builtin_amdgcn_mfma_f32_16x16x32_bf16(af[i], b3f[j], acc3[i][j], 0, 0, 0); \
                }                                                                   \
            __builtin_amdgcn_s_setprio(0);                                          \
        }                                                                           \
    }

    G1_STAGE(0, 0);
    __syncthreads();
#pragma unroll
    for (int t = 0; t < 8; t += 2) {
        G1_STAGE((t + 1) * 64, 1);
        G1_COMPUTE(0);
        __syncthreads();                 // drains vmcnt after compute: latency hidden
        if (t + 2 < 8) G1_STAGE((t + 2) * 64, 0);
        G1_COMPUTE(1);
        __syncthreads();
    }
#undef G1_STAGE
#undef G1_COMPUTE

    int lrow0 = (l >> 4) * 4, lcol = l & 15;
#pragma unroll
    for (int i = 0; i < 4; ++i)
#pragma unroll
        for (int j = 0; j < 2; ++j)
#pragma unroll
            for (int r = 0; r < 4; ++r) {
                int row = wm + i * 16 + lrow0 + r;
                int col = wn + j * 16 + lcol;
                float v1 = acc1[i][j][r];
                float v3 = acc3[i][j][r];
                float h = v1 / (1.f + __expf(-v1)) * v3;
                hbuf[(size_t)(m0 + row) * H_DIM + n0 + col] = f2bf(h);
            }
}

// ---------------- GEMM2: out[token] += w * (h W2), 128x128 tile, K=2048 ----------------
// Same double-buffered single-barrier pipeline. ltok/lw read from L2 in epilogue
// (keeps static LDS at exactly 64 KiB).
__global__ __launch_bounds__(256) void gemm2_kernel(
    const unsigned short* __restrict__ hbuf,
    const unsigned short* __restrict__ w2t,   // [E][D][H]
    const int* __restrict__ list_token,
    const float* __restrict__ list_w,
    const int* __restrict__ seg,
    float* __restrict__ out,
    int chunk_base, int MT) {
    __shared__ short As[2][128 * 64];
    __shared__ short Bs[2][128 * 64];

    int bfl = blockIdx.x;
    int xcd = bfl & 7;
    int idx = bfl >> 3;
    int yt = idx & 3;          // y-inner (D/128 = 4)
    int mlocal = idx >> 2;
    int mt = mlocal * 8 + xcd;
    if (mt >= MT) return;

    int tid = threadIdx.x;
    int w = tid >> 6, l = tid & 63;
    int m0 = mt * 128;
    int slot0 = chunk_base + m0;
    int n0 = yt * 128;

    int e = 0;
#pragma unroll
    for (int i = 0; i < E_NUM - 1; ++i) if (slot0 >= seg[i + 1]) e = i + 1;
    const unsigned short* b2 = w2t + ((size_t)e * D_DIM + n0) * H_DIM;

    int lr8 = l >> 3, p = l & 7;
    const unsigned short* aptr[4];
    const unsigned short* bptr[4];
#pragma unroll
    for (int q = 0; q < 4; ++q) {
        int row = (q * 4 + w) * 8 + lr8;       // 0..127
        int c = p ^ (row & 7);
        aptr[q] = hbuf + (size_t)(m0 + row) * H_DIM + c * 8;
        bptr[q] = b2 + (size_t)row * H_DIM + c * 8;
    }

    int wm = (w & 1) * 64;
    int wn = (w >> 1) * 64;
    int lrr = l & 15;
    int lk = (l >> 4) * 8;

    f32x4 acc[4][4] = {};

#define G2_STAGE(K0, BUF)                                                           \
    {                                                                               \
        _Pragma("unroll")                                                           \
        for (int q = 0; q < 4; ++q) {                                               \
            GLOAD_LDS16(aptr[q] + (K0), &As[BUF][(q * 4 + w) * 512]);               \
            GLOAD_LDS16(bptr[q] + (K0), &Bs[BUF][(q * 4 + w) * 512]);               \
        }                                                                           \
    }

#define G2_COMPUTE(BUF)                                                             \
    {                                                                               \
        _Pragma("unroll")                                                           \
        for (int ks = 0; ks < 64; ks += 32) {                                       \
            int cblk = (ks + lk) >> 3;                                              \
            bf16x8 af[4], bf[4];                                                    \
            _Pragma("unroll")                                                       \
            for (int i = 0; i < 4; ++i) {                                           \
                int row = wm + i * 16 + lrr;                                        \
                af[i] = *(const bf16x8*)&As[BUF][row * 64 + ((cblk ^ (row & 7)) << 3)]; \
            }                                                                       \
            _Pragma("unroll")                                                       \
            for (int j = 0; j < 4; ++j) {                                           \
                int row = wn + j * 16 + lrr;                                        \
                bf[j] = *(const bf16x8*)&Bs[BUF][row * 64 + ((cblk ^ (row & 7)) << 3)]; \
            }                                                                       \
            __builtin_amdgcn_s_setprio(1);                                          \
            _Pragma("unroll")                                                       \
            for (int i = 0; i < 4; ++i)                                             \
                _Pragma("unroll")                                                   \
                for (int j = 0; j < 4; ++j)                                         \
                    acc[i][j] = __builtin_amdgcn_mfma_f32_16x16x32_bf16(af[i], bf[j], acc[i][j], 0, 0, 0); \
            __builtin_amdgcn_s_setprio(0);                                          \
        }                                                                           \
    }

    G2_STAGE(0, 0);
    __syncthreads();
    for (int t = 0; t < 32; t += 2) {
        G2_STAGE((t + 1) * 64, 1);
        G2_COMPUTE(0);
        __syncthreads();
        if (t + 2 < 32) G2_STAGE((t + 2) * 64, 0);
        G2_COMPUTE(1);
        __syncthreads();
    }
#undef G2_STAGE
#undef G2_COMPUTE

    int lrow0 = (l >> 4) * 4, lcol = l & 15;
#pragma unroll
    for (int i = 0; i < 4; ++i)
#pragma unroll
        for (int r = 0; r < 4; ++r) {
            int row = wm + i * 16 + lrow0 + r;
            int tok = list_token[slot0 + row];
            if (tok < 0) continue;
            float wgt = list_w[slot0 + row];
#pragma unroll
            for (int j = 0; j < 4; ++j) {
                int col = wn + j * 16 + lcol;
                atomicAdd(&out[(size_t)tok * D_DIM + n0 + col], acc[i][j][r] * wgt);
            }
        }
}

extern "C" void kernel_launch(void* const* d_in, const int* in_sizes, int n_in,
                              void* d_out, int out_size, void* d_ws, size_t ws_size,
                              hipStream_t stream) {
    const float* x  = (const float*)d_in[0];
    const float* gw = (const float*)d_in[1];
    const float* W1 = (const float*)d_in[2];
    const float* W2 = (const float*)d_in[3];
    const float* W3 = (const float*)d_in[4];
    float* out = (float*)d_out;

    int T = in_sizes[0] / D_DIM;                 // 32768
    int npairs = T * TOPK_N;                     // 65536
    const int CAP = npairs + E_NUM * 128;        // 66560 = 520*128

    char* p = (char*)d_ws;
    size_t off = 0;
    auto take = [&](size_t bytes) {
        char* r = p + off;
        off = (off + bytes + 255) & ~(size_t)255;
        return r;
    };
    int* seg           = (int*)take((E_NUM + 1) * 4);
    int* partial       = (int*)take(64 * E_NUM * 4);
    int* block_base    = (int*)take(64 * E_NUM * 4);
    int* list_token    = (int*)take((size_t)CAP * 4);
    float* list_w      = (float*)take((size_t)CAP * 4);
    int* ridx          = (int*)take((size_t)npairs * 4);
    float* rw          = (float*)take((size_t)npairs * 4);
    float* gwT         = (float*)take((size_t)E_NUM * D_DIM * 4);
    unsigned short* zrow = (unsigned short*)take((size_t)D_DIM * 2);
    unsigned short* xb  = (unsigned short*)take((size_t)T * D_DIM * 2);
    unsigned short* w1t = (unsigned short*)take((size_t)E_NUM * D_DIM * H_DIM * 2);
    unsigned short* w3t = (unsigned short*)take((size_t)E_NUM * D_DIM * H_DIM * 2);
    unsigned short* w2t = (unsigned short*)take((size_t)E_NUM * D_DIM * H_DIM * 2);

    // Adaptive chunking: prefer 2 chunks (bigger gemm2 grid, fewer sync points)
    // if workspace can hold hbuf for CAP/2 slots; else fall back to 4.
    size_t hbuf2_bytes = (size_t)(CAP / 2) * H_DIM * 2;
    int NCHUNK = (ws_size >= off + hbuf2_bytes + 4096) ? 2 : 4;
    int chunk_slots = CAP / NCHUNK;              // multiple of 128
    int MT = chunk_slots / 128;
    int MG = (MT + 7) / 8;
    unsigned short* hbuf = (unsigned short*)take((size_t)chunk_slots * H_DIM * 2);

    hipMemsetAsync(d_out, 0, (size_t)out_size * sizeof(float), stream);

    init_kernel<<<(CAP + 255) / 256, 256, 0, stream>>>(list_token, list_w, zrow, CAP);
    gwt_kernel<<<(E_NUM * D_DIM) / 256, 256, 0, stream>>>(gw, gwT);

    gate_cvt_kernel<<<T / 4, 256, 0, stream>>>(x, gwT, xb, ridx, rw, T);

    dim3 tb(32, 8);
    tconv_kernel<<<dim3(H_DIM / 32, D_DIM / 32, E_NUM), tb, 0, stream>>>(W1, w1t, D_DIM, H_DIM);
    tconv_kernel<<<dim3(H_DIM / 32, D_DIM / 32, E_NUM), tb, 0, stream>>>(W3, w3t, D_DIM, H_DIM);
    tconv_kernel<<<dim3(D_DIM / 32, H_DIM / 32, E_NUM), tb, 0, stream>>>(W2, w2t, H_DIM, D_DIM);

    hist_kernel<<<64, 256, 0, stream>>>(ridx, partial, npairs);
    scan_kernel<<<1, 512, 0, stream>>>(partial, seg, block_base);
    scatter_kernel<<<64, 256, 0, stream>>>(ridx, rw, block_base, list_token, list_w, npairs);

    int g1_grid = 8 * MG * (H_DIM / 64);
    int g2_grid = 8 * MG * (D_DIM / 128);
    for (int c = 0; c < NCHUNK; ++c) {
        int cb = c * chunk_slots;
        gemm1_kernel<<<g1_grid, 256, 0, stream>>>(
            xb, w1t, w3t, zrow, list_token, seg, hbuf, cb, MT, MG);
        gemm2_kernel<<<g2_grid, 256, 0, stream>>>(
            hbuf, w2t, list_token, list_w, seg, out, cb, MT);
    }
}